// Round 6
// baseline (279.554 us; speedup 1.0000x reference)
//
#include <hip/hip_runtime.h>

// MHA fwd: B=4 S=2048 D=1024 H=16 HD=64. fp32 in/out, bf16 MFMA compute.
// R14: R13 GEMM-dbuf was null because __syncthreads() forces a vmcnt(0) drain
// at every barrier AND runtime-indexed LDS buffers defeat alias analysis ->
// prefetch drained before compute. Rebuild QKV GEMMs (Q|K + V merged) on the
// 8-phase principles: raw s_barrier + explicit counted waits (T4), two
// STATICALLY distinct LDS buffers (AA-provable disjoint), phase-split MFMA
// with setprio (T3+T5). 128x256 tile, BK=64, 512 thr = 8 waves (2Mx4N),
// 64x64/wave (acc 64 VGPR, no spill risk), grid (64,12)=768 = 3 exact
// rounds of 1 block/CU. Stage tile t+1 issued at top of tile t (lands ~2
// phases later; vmcnt(0) at tile end is cheap). Q|K blocks: swapped MFMA +
// MODE0 epilogue; V blocks: unswapped + MODE2 epilogue.
// Flash reverted to R11 exact (90.0us, 64 VGPR). Out-proj reverted to R0.

typedef unsigned short u16;
typedef __attribute__((ext_vector_type(4))) float f32x4;
typedef __attribute__((ext_vector_type(8))) short s16x8;
typedef __attribute__((ext_vector_type(4))) unsigned short u16x4;
typedef __attribute__((ext_vector_type(2))) unsigned int u32x2;
typedef __attribute__((ext_vector_type(4))) unsigned int u32x4;

#define DEV __device__ __forceinline__

#if __has_builtin(__builtin_amdgcn_exp2f)
#define EXP2(x) __builtin_amdgcn_exp2f(x)
#else
#define EXP2(x) exp2f(x)
#endif

DEV u16 f2b(float f) {  // fp32 -> bf16 RNE
  unsigned u = __float_as_uint(f);
  u += 0x7fffu + ((u >> 16) & 1u);
  return (u16)(u >> 16);
}

DEV unsigned pack2(float a, float b) {  // two fp32 -> packed bf16x2
#if __has_builtin(__builtin_amdgcn_cvt_pk_bf16_f32)
  typedef __attribute__((ext_vector_type(2))) __bf16 bf16x2;
  bf16x2 r = __builtin_amdgcn_cvt_pk_bf16_f32(a, b);
  return __builtin_bit_cast(unsigned, r);
#else
  return (unsigned)f2b(a) | ((unsigned)f2b(b) << 16);
#endif
}

DEV void async16(const void* g, void* l) {  // 16B global -> LDS direct
  __builtin_amdgcn_global_load_lds(
      (const __attribute__((address_space(1))) unsigned int*)g,
      (__attribute__((address_space(3))) unsigned int*)l, 16, 0, 0);
}

// ---------------- cast x -> bf16 ----------------
__global__ void k_cast(const float* __restrict__ x, u16* __restrict__ xb) {
  int i = (blockIdx.x * 256 + threadIdx.x) * 4;
  float4 v = *(const float4*)(x + i);
  u16x4 o;
  o.x = f2b(v.x); o.y = f2b(v.y); o.z = f2b(v.z); o.w = f2b(v.w);
  *(u16x4*)(xb + i) = o;
}

// ---------------- transpose+convert all 4 weights (1024x1024) -> Bt bf16 ----------------
__global__ void k_packw_all(const float* __restrict__ Wq, const float* __restrict__ Wk,
                            const float* __restrict__ Wv, const float* __restrict__ Wo,
                            u16* __restrict__ wt, u16* __restrict__ wot, float qscale) {
  const float* src; u16* dst; float scale = 1.0f;
  switch (blockIdx.z) {
    case 0: src = Wq; dst = wt; scale = qscale; break;
    case 1: src = Wk; dst = wt + 1024 * 1024; break;
    case 2: src = Wv; dst = wt + 2 * 1024 * 1024; break;
    default: src = Wo; dst = wot; break;
  }
  __shared__ float tile[32][33];
  int t = threadIdx.x;
  int k0 = blockIdx.x * 32, n0 = blockIdx.y * 32;
  int c = t & 31, r0 = t >> 5;
#pragma unroll
  for (int p = 0; p < 4; ++p) {
    int r = p * 8 + r0;
    tile[r][c] = src[(size_t)(k0 + r) * 1024 + n0 + c] * scale;
  }
  __syncthreads();
#pragma unroll
  for (int p = 0; p < 4; ++p) {
    int r = p * 8 + r0;
    dst[(size_t)(n0 + r) * 1024 + k0 + c] = f2b(tile[c][r]);
  }
}

__global__ void k_packbias(const float* __restrict__ bq, const float* __restrict__ bk,
                           const float* __restrict__ bv, float* __restrict__ out,
                           float qscale) {
  int t = blockIdx.x * 256 + threadIdx.x;
  float v = (t < 1024) ? bq[t] * qscale : (t < 2048 ? bk[t - 1024] : bv[t - 2048]);
  out[t] = v;
}

// ---------------- QKV GEMM: [Q|K|V] = xb(8192x1024) * wt(3072x1024)^T + b3 ----------------
// 128x256 tile, BK=64, 512 thr = 8 waves (2x4), 64x64 per wave.
// Two static LDS buffers (48KB each): A panel [128][64] + B panels [256][64],
// chunk-XOR swizzled ([row][cp] = global[row][cp^(row&7)]).
// Raw s_barrier + explicit vmcnt only (no __syncthreads in main loop).
#define QKV_STAGE(DST, kn)                                                \
  { const int ko = (kn) * 64;                                             \
    async16(aB + ko,          (DST) + 0 * 4096 + w * 512);                \
    async16(aB + 65536 + ko,  (DST) + 4096 + w * 512);                    \
    async16(bB + ko,          (DST) + 8192 + w * 512);                    \
    async16(bB + 65536 + ko,  (DST) + 12288 + w * 512);                   \
    async16(bB + 131072 + ko, (DST) + 16384 + w * 512);                   \
    async16(bB + 196608 + ko, (DST) + 20480 + w * 512); }

#define QKV_LOADFRAG(SRC, ks)                                             \
  { _Pragma("unroll") for (int mi = 0; mi < 4; ++mi) {                    \
      int r = wmE + mi * 16 + lane15;                                     \
      int c = (ks) * 4 + quad;                                            \
      af[mi] = *(const s16x8*)((SRC) + r * 64 + (c ^ (r & 7)) * 8);       \
    }                                                                     \
    _Pragma("unroll") for (int ni = 0; ni < 4; ++ni) {                    \
      int rn = wnE + ni * 16 + lane15;                                    \
      int c = (ks) * 4 + quad;                                            \
      bf[ni] = *(const s16x8*)((SRC) + 8192 + rn * 64 + (c ^ (rn & 7)) * 8); \
    } }

#define QKV_MFMA()                                                        \
  { __builtin_amdgcn_s_setprio(1);                                        \
    if (swapped) {                                                        \
      _Pragma("unroll") for (int mi = 0; mi < 4; ++mi)                    \
        _Pragma("unroll") for (int ni = 0; ni < 4; ++ni)                  \
          acc[mi][ni] = __builtin_amdgcn_mfma_f32_16x16x32_bf16(          \
              bf[ni], af[mi], acc[mi][ni], 0, 0, 0);                      \
    } else {                                                              \
      _Pragma("unroll") for (int mi = 0; mi < 4; ++mi)                    \
        _Pragma("unroll") for (int ni = 0; ni < 4; ++ni)                  \
          acc[mi][ni] = __builtin_amdgcn_mfma_f32_16x16x32_bf16(          \
              af[mi], bf[ni], acc[mi][ni], 0, 0, 0);                      \
    }                                                                     \
    __builtin_amdgcn_s_setprio(0); }

#define QKV_TILE(SRC, DST, kt, DO_STAGE)                                  \
  { if (DO_STAGE) QKV_STAGE(DST, (kt) + 1);                               \
    s16x8 af[4], bf[4];                                                   \
    QKV_LOADFRAG(SRC, 0);                                                 \
    __builtin_amdgcn_s_barrier();                                         \
    QKV_MFMA();                                                           \
    __builtin_amdgcn_s_barrier();                                         \
    QKV_LOADFRAG(SRC, 1);                                                 \
    __builtin_amdgcn_s_barrier();                                         \
    QKV_MFMA();                                                           \
    if (DO_STAGE) asm volatile("s_waitcnt vmcnt(0)" ::: "memory");        \
    __builtin_amdgcn_s_barrier(); }

__global__ __launch_bounds__(512, 1) void k_gemm_qkv(
    const u16* __restrict__ A, const u16* __restrict__ Bt,
    const float* __restrict__ bias, u16* __restrict__ qkv,
    u16* __restrict__ VT) {
  __shared__ u16 S0[24576];   // A [0,8192) | B [8192,24576)
  __shared__ u16 S1[24576];
  const int t = threadIdx.x;
  const int w = t >> 6, l = t & 63;
  const int lane15 = l & 15, quad = l >> 4;
  const int m0 = blockIdx.x * 128, n0 = blockIdx.y * 256;
  const bool swapped = (n0 < 2048);          // Q|K region vs V region
  const int wmE = (w >> 2) * 64, wnE = (w & 3) * 64;

  // staging source: thread covers row (unit*64 + w*8 + (l>>3)), chunk (l&7),
  // source chunk pre-swizzled so LDS[row][cp] = global[row][cp^(row&7)]
  const int srow8 = w * 8 + (l >> 3);
  const int gc = (l & 7) ^ ((l >> 3) & 7);
  const u16* aB = A + (size_t)(m0 + srow8) * 1024 + gc * 8;
  const u16* bB = Bt + (size_t)(n0 + srow8) * 1024 + gc * 8;

  f32x4 acc[4][4] = {};

  // prologue: stage tile 0 into S0, full drain once
  QKV_STAGE(S0, 0);
  asm volatile("s_waitcnt vmcnt(0)" ::: "memory");
  __builtin_amdgcn_s_barrier();

  // 16 K-tiles; even reads S0 / stages S1, odd reads S1 / stages S0
#pragma unroll 1
  for (int kp = 0; kp < 7; ++kp) {
    QKV_TILE(S0, S1, 2 * kp, true);
    QKV_TILE(S1, S0, 2 * kp + 1, true);
  }
  QKV_TILE(S0, S1, 14, true);
  QKV_TILE(S1, S0, 15, false);

  // epilogue: per-wave 4096-u16 LDS staging region (waves 0-5 in S0, 6-7 in S1)
  u16* W = (w < 6) ? (S0 + w * 4096) : (S1 + (w - 6) * 4096);
  const int l8 = l & 7, lr = l >> 3;

  if (swapped) {
    // acc[mi][ni][r]: row = m0+wmE+mi*16+lane15, col = n0+wnE+ni*16+quad*4+r
#pragma unroll
    for (int ni = 0; ni < 4; ++ni) {
      int gnb = n0 + wnE + ni * 16 + quad * 4;
      float4 bb = *(const float4*)(bias + gnb);
#pragma unroll
      for (int mi = 0; mi < 4; ++mi) {
        int mloc = mi * 16 + lane15;
        int nloc = ni * 16 + quad * 4;
        int blk = (nloc >> 3) ^ (mloc & 7);
        u32x2 o;
        o.x = pack2(acc[mi][ni][0] + bb.x, acc[mi][ni][1] + bb.y);
        o.y = pack2(acc[mi][ni][2] + bb.z, acc[mi][ni][3] + bb.w);
        *(u32x2*)(W + mloc * 64 + blk * 8 + (quad & 1) * 4) = o;
      }
    }
#pragma unroll
    for (int it = 0; it < 8; ++it) {
      int mloc = it * 8 + lr;
      int lb = l8 ^ (mloc & 7);
      s16x8 v = *(const s16x8*)(W + mloc * 64 + l8 * 8);
      int gm = m0 + wmE + mloc;
      *(s16x8*)(qkv + (size_t)gm * 2048 + n0 + wnE + lb * 8) = v;
    }
  } else {
    // unswapped: row = m0+wmE+mi*16+quad*4+r, col = n0+wnE+ni*16+lane15
#pragma unroll
    for (int ni = 0; ni < 4; ++ni) {
      int gn = n0 + wnE + ni * 16 + lane15;
      float bb = bias[gn];
#pragma unroll
      for (int mi = 0; mi < 4; ++mi) {
        int nloc = ni * 16 + lane15;
        int mloc = mi * 16 + quad * 4;
        int blk = (mloc >> 3) ^ (nloc & 7);
        u32x2 o;
        o.x = pack2(acc[mi][ni][0] + bb, acc[mi][ni][1] + bb);
        o.y = pack2(acc[mi][ni][2] + bb, acc[mi][ni][3] + bb);
        *(u32x2*)(W + nloc * 64 + blk * 8 + (quad & 1) * 4) = o;
      }
    }
#pragma unroll
    for (int it = 0; it < 8; ++it) {
      int nloc = it * 8 + lr;
      int lb = l8 ^ (nloc & 7);
      s16x8 v = *(const s16x8*)(W + nloc * 64 + l8 * 8);
      int gv = (n0 - 2048) + wnE + nloc;      // 0..1023
      int hh = gv >> 6, hd = gv & 63;
      int gm = m0 + wmE + lb * 8;             // 8 contiguous s
      int bb2 = gm >> 11, s = gm & 2047;
      *(s16x8*)(VT + (((size_t)(bb2 * 16 + hh) * 64 + hd) * 2048 + s)) = v;
    }
  }
}

// ---------------- out-proj GEMM (R0 single-buffered 128x128) ----------------
template <int MODE>
__global__ __launch_bounds__(256, 2) void k_gemm_bt(
    const u16* __restrict__ A, const u16* __restrict__ Bt,
    const float* __restrict__ bias, void* __restrict__ Cout, u16* __restrict__ VT,
    int K, int ldC, int nbase) {
  __shared__ u16 SH[16384];           // As [0,8192) | Bs [8192,16384)
  u16* As = SH;
  u16* Bs = SH + 8192;
  const int t = threadIdx.x;
  const int w = t >> 6, l = t & 63;
  const int lane15 = l & 15, quad = l >> 4;
  const int m0 = blockIdx.x * 128, n0 = nbase + blockIdx.y * 128;
  const int wm = (w >> 1) * 64, wn = (w & 1) * 64;

  const int srow = t >> 3, cp = t & 7;
  const u16* aSrc[4]; const u16* bSrc[4]; int ldsOff[4];
#pragma unroll
  for (int i = 0; i < 4; ++i) {
    int row = i * 32 + srow;
    int gcs = cp ^ (row & 7);
    aSrc[i] = A + (size_t)(m0 + row) * K + gcs * 8;
    bSrc[i] = Bt + (size_t)(n0 + row) * K + gcs * 8;
    ldsOff[i] = (i * 32 + w * 8) * 64;
  }

  f32x4 acc[4][4] = {};

  for (int kk = 0; kk < K; kk += 64) {
#pragma unroll
    for (int i = 0; i < 4; ++i) async16(aSrc[i] + kk, As + ldsOff[i]);
#pragma unroll
    for (int i = 0; i < 4; ++i) async16(bSrc[i] + kk, Bs + ldsOff[i]);
    __builtin_amdgcn_s_waitcnt(0);
    __syncthreads();

#pragma unroll
    for (int ks = 0; ks < 2; ++ks) {
      s16x8 af[4], bf[4];
#pragma unroll
      for (int mi = 0; mi < 4; ++mi) {
        int r = wm + mi * 16 + lane15;
        int c = ks * 4 + quad;
        af[mi] = *(const s16x8*)(As + r * 64 + (c ^ (r & 7)) * 8);
      }
#pragma unroll
      for (int ni = 0; ni < 4; ++ni) {
        int r = wn + ni * 16 + lane15;
        int c = ks * 4 + quad;
        bf[ni] = *(const s16x8*)(Bs + r * 64 + (c ^ (r & 7)) * 8);
      }
#pragma unroll
      for (int mi = 0; mi < 4; ++mi)
#pragma unroll
        for (int ni = 0; ni < 4; ++ni)
          acc[mi][ni] = (MODE == 0)
              ? __builtin_amdgcn_mfma_f32_16x16x32_bf16(bf[ni], af[mi], acc[mi][ni], 0, 0, 0)
              : __builtin_amdgcn_mfma_f32_16x16x32_bf16(af[mi], bf[ni], acc[mi][ni], 0, 0, 0);
    }
    __syncthreads();
  }

  if (MODE == 1) {
    // fp32 direct (64B segments per quad-row)
#pragma unroll
    for (int ni = 0; ni < 4; ++ni) {
      int gn = n0 + wn + ni * 16 + lane15;
      float bb = bias[gn];
#pragma unroll
      for (int mi = 0; mi < 4; ++mi) {
        int gmBase = m0 + wm + mi * 16 + quad * 4;
#pragma unroll
        for (int r = 0; r < 4; ++r)
          ((float*)Cout)[(size_t)(gmBase + r) * ldC + gn] = acc[mi][ni][r] + bb;
      }
    }
  }
}

// ---------------- flash attention (R11 exact: Bc=64, dbuf, 8 waves x 2 Q-tiles) ----------------
__global__ __launch_bounds__(512, 4) void k_flash(
    const u16* __restrict__ qkv, const u16* __restrict__ vt, u16* __restrict__ ctx) {
  __shared__ u16 S[2][8192];
  const int t = threadIdx.x;
  const int w = t >> 6, l = t & 63;
  const int lane15 = l & 15, quad = l >> 4;
  const int bh = blockIdx.x, qt = blockIdx.y;
  const int b = bh >> 4, h = bh & 15;

  int qrow[2];
  s16x8 qf[2][2];
#pragma unroll
  for (int T = 0; T < 2; ++T) {
    qrow[T] = b * 2048 + qt * 256 + w * 32 + T * 16 + lane15;
    const u16* qp = qkv + (size_t)qrow[T] * 2048 + h * 64 + quad * 8;
    qf[T][0] = *(const s16x8*)(qp);
    qf[T][1] = *(const s16x8*)(qp + 32);
  }

  const int srow = t >> 3, cp = t & 7;
  const int xks = (srow & 3) | (((srow >> 3) & 1) << 2);
  const u16* kSrc = qkv + (size_t)(b * 2048 + srow) * 2048 + 1024 + h * 64 + (cp ^ xks) * 8;
  const u16* vSrc = vt + (size_t)bh * (64 * 2048) + (size_t)srow * 2048 + (cp ^ (srow & 7)) * 8;
  const int kOff = w * 512;
  const int vOff = 4096 + w * 512;

  const int kr = (lane15 >> 2) * 8 + (lane15 & 3);
  f32x4 O[2][4] = {};
  float lsum[2] = {0.0f, 0.0f};
  const f32x4 ZERO4 = {};

  async16(kSrc, &S[0][kOff]);
  async16(vSrc, &S[0][vOff]);

  for (int jt = 0; jt < 32; ++jt) {
    __builtin_amdgcn_s_waitcnt(0);
    __syncthreads();
    const u16* Sb = S[jt & 1];
    if (jt < 31) {
      const size_t kAdv = (size_t)(jt + 1) * 64 * 2048;
      const int vAdv = (jt + 1) * 64;
      u16* D = S[(jt & 1) ^ 1];
      async16(kSrc + kAdv, D + kOff);
      async16(vSrc + vAdv, D + vOff);
    }

    f32x4 st[2][4];
    __builtin_amdgcn_s_setprio(1);
#pragma unroll
    for (int tt = 0; tt < 4; ++tt) {
      int rr = kr + (tt & 1) * 4 + (tt >> 1) * 32;
      int xk = (rr & 3) | (((rr >> 3) & 1) << 2);
      s16x8 kf = *(const s16x8*)(Sb + rr * 64 + ((0 * 4 + quad) ^ xk) * 8);
#pragma unroll
      for (int T = 0; T < 2; ++T)
        st[T][tt] = __builtin_amdgcn_mfma_f32_16x16x32_bf16(kf, qf[T][0], ZERO4, 0, 0, 0);
    }
#pragma unroll
    for (int tt = 0; tt < 4; ++tt) {
      int rr = kr + (tt & 1) * 4 + (tt >> 1) * 32;
      int xk = (rr & 3) | (((rr >> 3) & 1) << 2);
      s16x8 kf = *(const s16x8*)(Sb + rr * 64 + ((1 * 4 + quad) ^ xk) * 8);
#pragma unroll
      for (int T = 0; T < 2; ++T)
        st[T][tt] = __builtin_amdgcn_mfma_f32_16x16x32_bf16(kf, qf[T][1], st[T][tt], 0, 0, 0);
    }
    __builtin_amdgcn_s_setprio(0);

#pragma unroll
    for (int ks = 0; ks < 2; ++ks) {
      s16x8 pf[2];
#pragma unroll
      for (int T = 0; T < 2; ++T) {
        float p0 = EXP2(st[T][2 * ks][0]), p1 = EXP2(st[T][2 * ks][1]);
        float p2 = EXP2(st[T][2 * ks][2]), p3 = EXP2(st[T][2 * ks][3]);
        float p4 = EXP2(st[T][2 * ks + 1][0]), p5 = EXP2(st[T][2 * ks + 1][1]);
        float p6 = EXP2(st[T][2 * ks + 1][2]), p7 = EXP2(st[T][2 * ks + 1][3]);
        lsum[T] += ((p0 + p1) + (p2 + p3)) + ((p4 + p5) + (p6 + p7));
        u32x4 pu = {pack2(p0, p1), pack2(p2, p3), pack2(p4, p5), pack2(p6, p7)};
        pf[T] = __builtin_bit_cast(s16x8, pu);
      }
      const u16* Vh = Sb + 4096;
      int c7 = ks * 4 + quad;
      __builtin_amdgcn_s_setprio(1);
#pragma unroll
      for (int co = 0; co < 4; ++co) {
        int rr = co * 16 + lane15;
        s16x8 vf = *(const s16x8*)(Vh + rr * 64 + ((c7 ^ (rr & 7))) * 8);
#pragma unroll
        for (int T = 0; T < 2; ++T)
          O[T][co] = __builtin_amdgcn_mfma_f32_16x16x32_bf16(vf, pf[T], O[T][co], 0, 0, 0);
      }
      __builtin_amdgcn_s_setprio(0);
    }
  }

#pragma unroll
  for (int T = 0; T < 2; ++T) {
    lsum[T] += __shfl_xor(lsum[T], 16);
    lsum[T] += __shfl_xor(lsum[T], 32);
  }

#pragma unroll
  for (int T = 0; T < 2; ++T) {
    float inv = 1.0f / lsum[T];
#pragma unroll
    for (int co = 0; co < 4; ++co) {
      u32x2 o;
      o.x = pack2(O[T][co][0] * inv, O[T][co][1] * inv);
      o.y = pack2(O[T][co][2] * inv, O[T][co][3] * inv);
      *(u32x2*)(ctx + (size_t)qrow[T] * 1024 + h * 64 + co * 16 + quad * 4) = o;
    }
  }
}

// ---------------- workspace layout (bytes) ----------------
static constexpr size_t OFF_XB  = 0;                        // 16 MB  x bf16 (8192x1024)
static constexpr size_t OFF_WT  = OFF_XB + (16u << 20);     // 6 MB   Wqkv^T bf16 (3072x1024)
static constexpr size_t OFF_WOT = OFF_WT + (6u << 20);      // 2 MB   Wo^T bf16 (1024x1024)
static constexpr size_t OFF_B3  = OFF_WOT + (2u << 20);     // 64 KB  bias3072 fp32
static constexpr size_t OFF_QKV = OFF_B3 + (1u << 20);      // 32 MB  q|k bf16 (8192x2048)
static constexpr size_t OFF_VT  = OFF_QKV + (32u << 20);    // 16 MB  v^T bf16 (B,H,64,2048)
static constexpr size_t OFF_CTX = OFF_VT + (16u << 20);     // 16 MB  ctx bf16 (8192x1024)

extern "C" void kernel_launch(void* const* d_in, const int* in_sizes, int n_in,
                              void* d_out, int out_size, void* d_ws, size_t ws_size,
                              hipStream_t stream) {
  const float* x  = (const float*)d_in[0];
  const float* Wq = (const float*)d_in[1];
  const float* bq = (const float*)d_in[2];
  const float* Wk = (const float*)d_in[3];
  const float* bk = (const float*)d_in[4];
  const float* Wv = (const float*)d_in[5];
  const float* bv = (const float*)d_in[6];
  const float* Wo = (const float*)d_in[7];
  const float* bo = (const float*)d_in[8];
  char* ws = (char*)d_ws;
  u16* xb    = (u16*)(ws + OFF_XB);
  u16* wt    = (u16*)(ws + OFF_WT);
  u16* wot   = (u16*)(ws + OFF_WOT);
  float* b3  = (float*)(ws + OFF_B3);
  u16* qkv   = (u16*)(ws + OFF_QKV);
  u16* vtb   = (u16*)(ws + OFF_VT);
  u16* ctx   = (u16*)(ws + OFF_CTX);
  float* out = (float*)d_out;

  const float QSCALE = 0.125f * 1.44269504f;  // 1/sqrt(64) * log2(e): exp2-domain scores

  k_cast<<<8192, 256, 0, stream>>>(x, xb);
  k_packw_all<<<dim3(32, 32, 4), 256, 0, stream>>>(Wq, Wk, Wv, Wo, wt, wot, QSCALE);
  k_packbias<<<12, 256, 0, stream>>>(bq, bk, bv, b3, QSCALE);
  // merged QKV projections: 128x256 tiles over N=3072 (Q|K -> qkv, V -> vtb)
  k_gemm_qkv<<<dim3(64, 12), 512, 0, stream>>>(xb, wt, b3, qkv, vtb);
  // flash: grid (64 bh, 8 qt); 512 thr, 8 waves, Bc=64 (R11 exact)
  k_flash<<<dim3(64, 8), 512, 0, stream>>>(qkv, vtb, ctx);
  // out projection -> fp32 d_out
  k_gemm_bt<1><<<dim3(64, 8), 256, 0, stream>>>(ctx, wot, bo, out, nullptr, 1024, 1024, 0);
}

// Round 8
// 264.669 us; speedup vs baseline: 1.0562x; 1.0562x over previous
//
#include <hip/hip_runtime.h>

// MHA fwd: B=4 S=2048 D=1024 H=16 HD=64. fp32 in/out, bf16 MFMA compute.
// R16: R15 NaN root-caused — cross-wave race at tile 0 ONLY. Safety needs each
// wave's loads for tile kt confirmed (its own vmcnt) BEFORE it reaches barrier
// kt; true for kt>=2 (confirm at tile kt-1's vmcnt(6)) but kt0's confirm was
// AFTER barrier 0, so wave A could read wave B's kt0 rows before B's DMA
// landed -> garbage -> exp2 -> inf -> NaN. Fix: ONE prologue
// s_waitcnt vmcnt(6) (confirm kt0 before the first barrier), per the m218
// template's prologue-confirm pattern. Schedule otherwise identical:
// tri-buffered 144KB LDS, stage kt+2 at tile kt, one s_barrier/tile,
// counted vmcnt(6) -> ~2-tile load flight, no hot drain.
// Flash = R11-exact (90us best measured). Out-proj unchanged.

typedef unsigned short u16;
typedef __attribute__((ext_vector_type(4))) float f32x4;
typedef __attribute__((ext_vector_type(8))) short s16x8;
typedef __attribute__((ext_vector_type(4))) unsigned short u16x4;
typedef __attribute__((ext_vector_type(2))) unsigned int u32x2;
typedef __attribute__((ext_vector_type(4))) unsigned int u32x4;

#define DEV __device__ __forceinline__

#if __has_builtin(__builtin_amdgcn_exp2f)
#define EXP2(x) __builtin_amdgcn_exp2f(x)
#else
#define EXP2(x) exp2f(x)
#endif

DEV u16 f2b(float f) {  // fp32 -> bf16 RNE
  unsigned u = __float_as_uint(f);
  u += 0x7fffu + ((u >> 16) & 1u);
  return (u16)(u >> 16);
}

DEV unsigned pack2(float a, float b) {  // two fp32 -> packed bf16x2
#if __has_builtin(__builtin_amdgcn_cvt_pk_bf16_f32)
  typedef __attribute__((ext_vector_type(2))) __bf16 bf16x2;
  bf16x2 r = __builtin_amdgcn_cvt_pk_bf16_f32(a, b);
  return __builtin_bit_cast(unsigned, r);
#else
  return (unsigned)f2b(a) | ((unsigned)f2b(b) << 16);
#endif
}

DEV void async16(const void* g, void* l) {  // 16B global -> LDS direct
  __builtin_amdgcn_global_load_lds(
      (const __attribute__((address_space(1))) unsigned int*)g,
      (__attribute__((address_space(3))) unsigned int*)l, 16, 0, 0);
}

// ---------------- cast x -> bf16 ----------------
__global__ void k_cast(const float* __restrict__ x, u16* __restrict__ xb) {
  int i = (blockIdx.x * 256 + threadIdx.x) * 4;
  float4 v = *(const float4*)(x + i);
  u16x4 o;
  o.x = f2b(v.x); o.y = f2b(v.y); o.z = f2b(v.z); o.w = f2b(v.w);
  *(u16x4*)(xb + i) = o;
}

// ---------------- transpose+convert all 4 weights (1024x1024) -> Bt bf16 ----------------
__global__ void k_packw_all(const float* __restrict__ Wq, const float* __restrict__ Wk,
                            const float* __restrict__ Wv, const float* __restrict__ Wo,
                            u16* __restrict__ wt, u16* __restrict__ wot, float qscale) {
  const float* src; u16* dst; float scale = 1.0f;
  switch (blockIdx.z) {
    case 0: src = Wq; dst = wt; scale = qscale; break;
    case 1: src = Wk; dst = wt + 1024 * 1024; break;
    case 2: src = Wv; dst = wt + 2 * 1024 * 1024; break;
    default: src = Wo; dst = wot; break;
  }
  __shared__ float tile[32][33];
  int t = threadIdx.x;
  int k0 = blockIdx.x * 32, n0 = blockIdx.y * 32;
  int c = t & 31, r0 = t >> 5;
#pragma unroll
  for (int p = 0; p < 4; ++p) {
    int r = p * 8 + r0;
    tile[r][c] = src[(size_t)(k0 + r) * 1024 + n0 + c] * scale;
  }
  __syncthreads();
#pragma unroll
  for (int p = 0; p < 4; ++p) {
    int r = p * 8 + r0;
    dst[(size_t)(n0 + r) * 1024 + k0 + c] = f2b(tile[c][r]);
  }
}

__global__ void k_packbias(const float* __restrict__ bq, const float* __restrict__ bk,
                           const float* __restrict__ bv, float* __restrict__ out,
                           float qscale) {
  int t = blockIdx.x * 256 + threadIdx.x;
  float v = (t < 1024) ? bq[t] * qscale : (t < 2048 ? bk[t - 1024] : bv[t - 2048]);
  out[t] = v;
}

// ---------------- QKV GEMM: [Q|K|V] = xb(8192x1024) * wt(3072x1024)^T + b3 ----------------
// 128x256 tile, BK=64, 512 thr = 8 waves (2Mx4N), 64x64 out per wave.
// Tri-buffered LDS (3 x 24576 u16: A[128][64] | B[256][64]), chunk-XOR swizzle.
// Tile kt: s_barrier; stage kt+2 -> buf (kt+2)%3; vmcnt(6); ds_read+MFMA.
// Cross-wave safety: each wave confirms tile kt's loads BEFORE barrier kt
// (prologue vmcnt(6) for kt0; tile kt-1's vmcnt(6) for kt>=1).
#define QSTAGE(BUFB, ktv)                                               \
  { const int ko = (ktv) * 64;                                          \
    async16(aP + ko,          S + (BUFB) + ldsW);                       \
    async16(aP + ko + 65536,  S + (BUFB) + 4096 + ldsW);                \
    async16(bP + ko,          S + (BUFB) + 8192 + ldsW);                \
    async16(bP + ko + 65536,  S + (BUFB) + 12288 + ldsW);               \
    async16(bP + ko + 131072, S + (BUFB) + 16384 + ldsW);               \
    async16(bP + ko + 196608, S + (BUFB) + 20480 + ldsW); }

#define QCOMP(BUFB)                                                     \
  { _Pragma("unroll")                                                   \
    for (int ks = 0; ks < 2; ++ks) {                                    \
      s16x8 af[4], bf[4];                                               \
      _Pragma("unroll") for (int mi = 0; mi < 4; ++mi) {                \
        int r = wmE + mi * 16 + lane15;                                 \
        int c = ks * 4 + quad;                                          \
        af[mi] = *(const s16x8*)(S + (BUFB) + r * 64 + (c ^ (r & 7)) * 8); \
      }                                                                 \
      _Pragma("unroll") for (int ni = 0; ni < 4; ++ni) {                \
        int rn = wnE + ni * 16 + lane15;                                \
        int c = ks * 4 + quad;                                          \
        bf[ni] = *(const s16x8*)(S + (BUFB) + 8192 + rn * 64 + (c ^ (rn & 7)) * 8); \
      }                                                                 \
      __builtin_amdgcn_s_setprio(1);                                    \
      if (swapped) {                                                    \
        _Pragma("unroll") for (int mi = 0; mi < 4; ++mi)                \
          _Pragma("unroll") for (int ni = 0; ni < 4; ++ni)              \
            acc[mi][ni] = __builtin_amdgcn_mfma_f32_16x16x32_bf16(      \
                bf[ni], af[mi], acc[mi][ni], 0, 0, 0);                  \
      } else {                                                          \
        _Pragma("unroll") for (int mi = 0; mi < 4; ++mi)                \
          _Pragma("unroll") for (int ni = 0; ni < 4; ++ni)              \
            acc[mi][ni] = __builtin_amdgcn_mfma_f32_16x16x32_bf16(      \
                af[mi], bf[ni], acc[mi][ni], 0, 0, 0);                  \
      }                                                                 \
      __builtin_amdgcn_s_setprio(0);                                    \
    } }

#define GTILE(CURB, NXTB, ktv, DOSTAGE)                                 \
  { __builtin_amdgcn_s_barrier();                                       \
    if (DOSTAGE) {                                                      \
      QSTAGE(NXTB, (ktv) + 2);                                          \
      asm volatile("s_waitcnt vmcnt(6)" ::: "memory");                  \
    } else {                                                            \
      asm volatile("s_waitcnt vmcnt(0)" ::: "memory");                  \
    }                                                                   \
    QCOMP(CURB) }

__global__ __launch_bounds__(512, 1) void k_gemm_qkv(
    const u16* __restrict__ A, const u16* __restrict__ Bt,
    const float* __restrict__ bias, u16* __restrict__ qkv,
    u16* __restrict__ VT) {
  __shared__ u16 S[73728];              // 3 bufs x 24576 (A 8192 | B 16384)
  const int t = threadIdx.x;
  const int w = t >> 6, l = t & 63;
  const int lane15 = l & 15, quad = l >> 4;
  const int m0 = blockIdx.x * 128, n0 = blockIdx.y * 256;
  const bool swapped = (n0 < 2048);     // Q|K region vs V region
  const int wmE = (w >> 2) * 64, wnE = (w & 3) * 64;

  // staging: thread covers row (j*64 + w*8 + (l>>3)), chunk (l&7);
  // source chunk pre-swizzled so LDS[row][cp] = global[row][cp^(row&7)];
  // global_load_lds puts lane l at wave-base + l*16B = row*128B + (l&7)*16B.
  const int gc = (l & 7) ^ ((l >> 3) & 7);
  const u16* aP = A  + (size_t)(m0 + w * 8 + (l >> 3)) * 1024 + gc * 8;
  const u16* bP = Bt + (size_t)(n0 + w * 8 + (l >> 3)) * 1024 + gc * 8;
  const int ldsW = w * 512;             // wave-uniform LDS base (elements)

  f32x4 acc[4][4] = {};

  // prologue: stage tiles 0,1 into bufs 0,1 (12 loads), then CONFIRM kt0's 6
  // before the first barrier — this is the cross-wave handshake R15 missed.
  QSTAGE(0, 0);
  QSTAGE(24576, 1);
  asm volatile("s_waitcnt vmcnt(6)" ::: "memory");

  // 16 K-tiles; buf = kt%3. Tile kt stages kt+2 into (kt+2)%3.
#pragma unroll 1
  for (int j = 0; j < 4; ++j) {
    int kt = 3 * j;
    GTILE(0,     49152, kt,     1);
    GTILE(24576, 0,     kt + 1, 1);
    GTILE(49152, 24576, kt + 2, 1);
  }
  GTILE(0,     49152, 12, 1);   // stages kt14 -> buf2
  GTILE(24576, 0,     13, 1);   // stages kt15 -> buf0
  GTILE(49152, 24576, 14, 0);   // vmcnt(0): kt15 landed
  GTILE(0,     0,     15, 0);   // vmcnt(0) free

  __syncthreads();              // all reads done before epilogue LDS reuse

  // epilogue: per-wave 4096-u16 LDS staging region
  u16* W = S + w * 4096;
  const int l8 = l & 7, lr = l >> 3;

  if (swapped) {
    // acc[mi][ni][r]: row = m0+wmE+mi*16+lane15, col = n0+wnE+ni*16+quad*4+r
#pragma unroll
    for (int ni = 0; ni < 4; ++ni) {
      int gnb = n0 + wnE + ni * 16 + quad * 4;
      float4 bb = *(const float4*)(bias + gnb);
#pragma unroll
      for (int mi = 0; mi < 4; ++mi) {
        int mloc = mi * 16 + lane15;
        int nloc = ni * 16 + quad * 4;
        int blk = (nloc >> 3) ^ (mloc & 7);
        u32x2 o;
        o.x = pack2(acc[mi][ni][0] + bb.x, acc[mi][ni][1] + bb.y);
        o.y = pack2(acc[mi][ni][2] + bb.z, acc[mi][ni][3] + bb.w);
        *(u32x2*)(W + mloc * 64 + blk * 8 + (quad & 1) * 4) = o;
      }
    }
#pragma unroll
    for (int it = 0; it < 8; ++it) {
      int mloc = it * 8 + lr;
      int lb = l8 ^ (mloc & 7);
      s16x8 v = *(const s16x8*)(W + mloc * 64 + l8 * 8);
      int gm = m0 + wmE + mloc;
      *(s16x8*)(qkv + (size_t)gm * 2048 + n0 + wnE + lb * 8) = v;
    }
  } else {
    // unswapped: row = m0+wmE+mi*16+quad*4+r, col = n0+wnE+ni*16+lane15
#pragma unroll
    for (int ni = 0; ni < 4; ++ni) {
      int gn = n0 + wnE + ni * 16 + lane15;
      float bb = bias[gn];
#pragma unroll
      for (int mi = 0; mi < 4; ++mi) {
        int nloc = ni * 16 + lane15;
        int mloc = mi * 16 + quad * 4;
        int blk = (mloc >> 3) ^ (nloc & 7);
        u32x2 o;
        o.x = pack2(acc[mi][ni][0] + bb, acc[mi][ni][1] + bb);
        o.y = pack2(acc[mi][ni][2] + bb, acc[mi][ni][3] + bb);
        *(u32x2*)(W + nloc * 64 + blk * 8 + (quad & 1) * 4) = o;
      }
    }
#pragma unroll
    for (int it = 0; it < 8; ++it) {
      int nloc = it * 8 + lr;
      int lb = l8 ^ (nloc & 7);
      s16x8 v = *(const s16x8*)(W + nloc * 64 + l8 * 8);
      int gv = (n0 - 2048) + wnE + nloc;      // 0..1023
      int hh = gv >> 6, hd = gv & 63;
      int gm = m0 + wmE + lb * 8;             // 8 contiguous s
      int bb2 = gm >> 11, s = gm & 2047;
      *(s16x8*)(VT + (((size_t)(bb2 * 16 + hh) * 64 + hd) * 2048 + s)) = v;
    }
  }
}

// ---------------- out-proj GEMM (R0 single-buffered 128x128) ----------------
template <int MODE>
__global__ __launch_bounds__(256, 2) void k_gemm_bt(
    const u16* __restrict__ A, const u16* __restrict__ Bt,
    const float* __restrict__ bias, void* __restrict__ Cout, u16* __restrict__ VT,
    int K, int ldC, int nbase) {
  __shared__ u16 SH[16384];           // As [0,8192) | Bs [8192,16384)
  u16* As = SH;
  u16* Bs = SH + 8192;
  const int t = threadIdx.x;
  const int w = t >> 6, l = t & 63;
  const int lane15 = l & 15, quad = l >> 4;
  const int m0 = blockIdx.x * 128, n0 = nbase + blockIdx.y * 128;
  const int wm = (w >> 1) * 64, wn = (w & 1) * 64;

  const int srow = t >> 3, cp = t & 7;
  const u16* aSrc[4]; const u16* bSrc[4]; int ldsOff[4];
#pragma unroll
  for (int i = 0; i < 4; ++i) {
    int row = i * 32 + srow;
    int gcs = cp ^ (row & 7);
    aSrc[i] = A + (size_t)(m0 + row) * K + gcs * 8;
    bSrc[i] = Bt + (size_t)(n0 + row) * K + gcs * 8;
    ldsOff[i] = (i * 32 + w * 8) * 64;
  }

  f32x4 acc[4][4] = {};

  for (int kk = 0; kk < K; kk += 64) {
#pragma unroll
    for (int i = 0; i < 4; ++i) async16(aSrc[i] + kk, As + ldsOff[i]);
#pragma unroll
    for (int i = 0; i < 4; ++i) async16(bSrc[i] + kk, Bs + ldsOff[i]);
    __builtin_amdgcn_s_waitcnt(0);
    __syncthreads();

#pragma unroll
    for (int ks = 0; ks < 2; ++ks) {
      s16x8 af[4], bf[4];
#pragma unroll
      for (int mi = 0; mi < 4; ++mi) {
        int r = wm + mi * 16 + lane15;
        int c = ks * 4 + quad;
        af[mi] = *(const s16x8*)(As + r * 64 + (c ^ (r & 7)) * 8);
      }
#pragma unroll
      for (int ni = 0; ni < 4; ++ni) {
        int r = wn + ni * 16 + lane15;
        int c = ks * 4 + quad;
        bf[ni] = *(const s16x8*)(Bs + r * 64 + (c ^ (r & 7)) * 8);
      }
#pragma unroll
      for (int mi = 0; mi < 4; ++mi)
#pragma unroll
        for (int ni = 0; ni < 4; ++ni)
          acc[mi][ni] = (MODE == 0)
              ? __builtin_amdgcn_mfma_f32_16x16x32_bf16(bf[ni], af[mi], acc[mi][ni], 0, 0, 0)
              : __builtin_amdgcn_mfma_f32_16x16x32_bf16(af[mi], bf[ni], acc[mi][ni], 0, 0, 0);
    }
    __syncthreads();
  }

  if (MODE == 1) {
    // fp32 direct (64B segments per quad-row)
#pragma unroll
    for (int ni = 0; ni < 4; ++ni) {
      int gn = n0 + wn + ni * 16 + lane15;
      float bb = bias[gn];
#pragma unroll
      for (int mi = 0; mi < 4; ++mi) {
        int gmBase = m0 + wm + mi * 16 + quad * 4;
#pragma unroll
        for (int r = 0; r < 4; ++r)
          ((float*)Cout)[(size_t)(gmBase + r) * ldC + gn] = acc[mi][ni][r] + bb;
      }
    }
  }
}

// ---------------- flash attention (R11 exact: Bc=64, dbuf, 8 waves x 2 Q-tiles) ----------------
__global__ __launch_bounds__(512, 4) void k_flash(
    const u16* __restrict__ qkv, const u16* __restrict__ vt, u16* __restrict__ ctx) {
  __shared__ u16 S[2][8192];
  const int t = threadIdx.x;
  const int w = t >> 6, l = t & 63;
  const int lane15 = l & 15, quad = l >> 4;
  const int bh = blockIdx.x, qt = blockIdx.y;
  const int b = bh >> 4, h = bh & 15;

  int qrow[2];
  s16x8 qf[2][2];
#pragma unroll
  for (int T = 0; T < 2; ++T) {
    qrow[T] = b * 2048 + qt * 256 + w * 32 + T * 16 + lane15;
    const u16* qp = qkv + (size_t)qrow[T] * 2048 + h * 64 + quad * 8;
    qf[T][0] = *(const s16x8*)(qp);
    qf[T][1] = *(const s16x8*)(qp + 32);
  }

  const int srow = t >> 3, cp = t & 7;
  const int xks = (srow & 3) | (((srow >> 3) & 1) << 2);
  const u16* kSrc = qkv + (size_t)(b * 2048 + srow) * 2048 + 1024 + h * 64 + (cp ^ xks) * 8;
  const u16* vSrc = vt + (size_t)bh * (64 * 2048) + (size_t)srow * 2048 + (cp ^ (srow & 7)) * 8;
  const int kOff = w * 512;
  const int vOff = 4096 + w * 512;

  const int kr = (lane15 >> 2) * 8 + (lane15 & 3);
  f32x4 O[2][4] = {};
  float lsum[2] = {0.0f, 0.0f};
  const f32x4 ZERO4 = {};

  async16(kSrc, &S[0][kOff]);
  async16(vSrc, &S[0][vOff]);

  for (int jt = 0; jt < 32; ++jt) {
    __builtin_amdgcn_s_waitcnt(0);
    __syncthreads();
    const u16* Sb = S[jt & 1];
    if (jt < 31) {
      const size_t kAdv = (size_t)(jt + 1) * 64 * 2048;
      const int vAdv = (jt + 1) * 64;
      u16* D = S[(jt & 1) ^ 1];
      async16(kSrc + kAdv, D + kOff);
      async16(vSrc + vAdv, D + vOff);
    }

    f32x4 st[2][4];
    __builtin_amdgcn_s_setprio(1);
#pragma unroll
    for (int tt = 0; tt < 4; ++tt) {
      int rr = kr + (tt & 1) * 4 + (tt >> 1) * 32;
      int xk = (rr & 3) | (((rr >> 3) & 1) << 2);
      s16x8 kf = *(const s16x8*)(Sb + rr * 64 + ((0 * 4 + quad) ^ xk) * 8);
#pragma unroll
      for (int T = 0; T < 2; ++T)
        st[T][tt] = __builtin_amdgcn_mfma_f32_16x16x32_bf16(kf, qf[T][0], ZERO4, 0, 0, 0);
    }
#pragma unroll
    for (int tt = 0; tt < 4; ++tt) {
      int rr = kr + (tt & 1) * 4 + (tt >> 1) * 32;
      int xk = (rr & 3) | (((rr >> 3) & 1) << 2);
      s16x8 kf = *(const s16x8*)(Sb + rr * 64 + ((1 * 4 + quad) ^ xk) * 8);
#pragma unroll
      for (int T = 0; T < 2; ++T)
        st[T][tt] = __builtin_amdgcn_mfma_f32_16x16x32_bf16(kf, qf[T][1], st[T][tt], 0, 0, 0);
    }
    __builtin_amdgcn_s_setprio(0);

#pragma unroll
    for (int ks = 0; ks < 2; ++ks) {
      s16x8 pf[2];
#pragma unroll
      for (int T = 0; T < 2; ++T) {
        float p0 = EXP2(st[T][2 * ks][0]), p1 = EXP2(st[T][2 * ks][1]);
        float p2 = EXP2(st[T][2 * ks][2]), p3 = EXP2(st[T][2 * ks][3]);
        float p4 = EXP2(st[T][2 * ks + 1][0]), p5 = EXP2(st[T][2 * ks + 1][1]);
        float p6 = EXP2(st[T][2 * ks + 1][2]), p7 = EXP2(st[T][2 * ks + 1][3]);
        lsum[T] += ((p0 + p1) + (p2 + p3)) + ((p4 + p5) + (p6 + p7));
        u32x4 pu = {pack2(p0, p1), pack2(p2, p3), pack2(p4, p5), pack2(p6, p7)};
        pf[T] = __builtin_bit_cast(s16x8, pu);
      }
      const u16* Vh = Sb + 4096;
      int c7 = ks * 4 + quad;
      __builtin_amdgcn_s_setprio(1);
#pragma unroll
      for (int co = 0; co < 4; ++co) {
        int rr = co * 16 + lane15;
        s16x8 vf = *(const s16x8*)(Vh + rr * 64 + ((c7 ^ (rr & 7))) * 8);
#pragma unroll
        for (int T = 0; T < 2; ++T)
          O[T][co] = __builtin_amdgcn_mfma_f32_16x16x32_bf16(vf, pf[T], O[T][co], 0, 0, 0);
      }
      __builtin_amdgcn_s_setprio(0);
    }
  }

#pragma unroll
  for (int T = 0; T < 2; ++T) {
    lsum[T] += __shfl_xor(lsum[T], 16);
    lsum[T] += __shfl_xor(lsum[T], 32);
  }

#pragma unroll
  for (int T = 0; T < 2; ++T) {
    float inv = 1.0f / lsum[T];
#pragma unroll
    for (int co = 0; co < 4; ++co) {
      u32x2 o;
      o.x = pack2(O[T][co][0] * inv, O[T][co][1] * inv);
      o.y = pack2(O[T][co][2] * inv, O[T][co][3] * inv);
      *(u32x2*)(ctx + (size_t)qrow[T] * 1024 + h * 64 + co * 16 + quad * 4) = o;
    }
  }
}

// ---------------- workspace layout (bytes) ----------------
static constexpr size_t OFF_XB  = 0;                        // 16 MB  x bf16 (8192x1024)
static constexpr size_t OFF_WT  = OFF_XB + (16u << 20);     // 6 MB   Wqkv^T bf16 (3072x1024)
static constexpr size_t OFF_WOT = OFF_WT + (6u << 20);      // 2 MB   Wo^T bf16 (1024x1024)
static constexpr size_t OFF_B3  = OFF_WOT + (2u << 20);     // 64 KB  bias3072 fp32
static constexpr size_t OFF_QKV = OFF_B3 + (1u << 20);      // 32 MB  q|k bf16 (8192x2048)
static constexpr size_t OFF_VT  = OFF_QKV + (32u << 20);    // 16 MB  v^T bf16 (B,H,64,2048)
static constexpr size_t OFF_CTX = OFF_VT + (16u << 20);     // 16 MB  ctx bf16 (8192x1024)

extern "C" void kernel_launch(void* const* d_in, const int* in_sizes, int n_in,
                              void* d_out, int out_size, void* d_ws, size_t ws_size,
                              hipStream_t stream) {
  const float* x  = (const float*)d_in[0];
  const float* Wq = (const float*)d_in[1];
  const float* bq = (const float*)d_in[2];
  const float* Wk = (const float*)d_in[3];
  const float* bk = (const float*)d_in[4];
  const float* Wv = (const float*)d_in[5];
  const float* bv = (const float*)d_in[6];
  const float* Wo = (const float*)d_in[7];
  const float* bo = (const float*)d_in[8];
  char* ws = (char*)d_ws;
  u16* xb    = (u16*)(ws + OFF_XB);
  u16* wt    = (u16*)(ws + OFF_WT);
  u16* wot   = (u16*)(ws + OFF_WOT);
  float* b3  = (float*)(ws + OFF_B3);
  u16* qkv   = (u16*)(ws + OFF_QKV);
  u16* vtb   = (u16*)(ws + OFF_VT);
  u16* ctx   = (u16*)(ws + OFF_CTX);
  float* out = (float*)d_out;

  const float QSCALE = 0.125f * 1.44269504f;  // 1/sqrt(64) * log2(e): exp2-domain scores

  k_cast<<<8192, 256, 0, stream>>>(x, xb);
  k_packw_all<<<dim3(32, 32, 4), 256, 0, stream>>>(Wq, Wk, Wv, Wo, wt, wot, QSCALE);
  k_packbias<<<12, 256, 0, stream>>>(bq, bk, bv, b3, QSCALE);
  // merged QKV projections: 128x256 tiles over N=3072 (Q|K -> qkv, V -> vtb)
  k_gemm_qkv<<<dim3(64, 12), 512, 0, stream>>>(xb, wt, b3, qkv, vtb);
  // flash: grid (64 bh, 8 qt); 512 thr, 8 waves, Bc=64 (R11 exact)
  k_flash<<<dim3(64, 8), 512, 0, stream>>>(qkv, vtb, ctx);
  // out projection -> fp32 d_out
  k_gemm_bt<1><<<dim3(64, 8), 256, 0, stream>>>(ctx, wot, bo, out, nullptr, 1024, 1024, 0);
}